// Round 14
// baseline (2799.625 us; speedup 1.0000x reference)
//
#include <hip/hip_runtime.h>
#include <hip/hip_bf16.h>

#define S_LEN 2048
#define D_DIM 128
#define BH_N  64
#define BC    64
#define SCALE 0.08838834764831845f
#define SD    (S_LEN * D_DIM)

#define FLAGS_OFF  4096
#define LSUM_OFF   16384
#define KB16_OFF   (LSUM_OFF + 524288)
#define WS_SYNC    ((size_t)KB16_OFF)
#define WS_SYNC16  ((size_t)KB16_OFF + (size_t)BH_N * SD * 2)

typedef __attribute__((ext_vector_type(8)))  short short8;
typedef __attribute__((ext_vector_type(16))) float f32x16;
typedef __attribute__((ext_vector_type(4)))  float fv4;

__device__ __forceinline__ ushort f2bf(float f) {
  union { float f; unsigned u; } x; x.f = f;
  unsigned r = x.u + 0x7FFFu + ((x.u >> 16) & 1u);
  return (ushort)(r >> 16);
}

__device__ __forceinline__ short8 pack8(float4 a, float4 b) {
  short8 p;
  p[0] = (short)f2bf(a.x); p[1] = (short)f2bf(a.y);
  p[2] = (short)f2bf(a.z); p[3] = (short)f2bf(a.w);
  p[4] = (short)f2bf(b.x); p[5] = (short)f2bf(b.y);
  p[6] = (short)f2bf(b.z); p[7] = (short)f2bf(b.w);
  return p;
}

// ============ init: zero per-XCD counters + flags (every launch) =============
__global__ __launch_bounds__(256) void init_kernel(unsigned* ws) {
  for (int i = threadIdx.x; i < LSUM_OFF / 4; i += 256) ws[i] = 0u;
}

// ===================== cvt: K fp32 -> bf16 (RNE, = f2bf) =====================
__global__ __launch_bounds__(256) void cvt_k_kernel(
    const float* __restrict__ k, ushort* __restrict__ kb) {
  size_t total = (size_t)BH_N * SD / 8;
  for (size_t i = (size_t)blockIdx.x * 256 + threadIdx.x; i < total;
       i += (size_t)gridDim.x * 256) {
    float4 a = *(const float4*)(k + i * 8);
    float4 b = *(const float4*)(k + i * 8 + 4);
    *(short8*)(kb + i * 8) = pack8(a, b);
  }
}

// ================== A-item: flash ctx (+ optional lsum publish) ==============
template <bool KB16, bool PUB>
__device__ __forceinline__ void do_A(
    int bh, int qb,
    const float* __restrict__ q, const float* __restrict__ k,
    const ushort* __restrict__ kb, const float* __restrict__ v,
    float* __restrict__ ctx, float* __restrict__ lsum_out,
    unsigned* __restrict__ flags,
    char* klds, char* vtlds, char* plds, float (*lred)[64]) {
  const int tid  = threadIdx.x;
  const int lane = tid & 63;
  const int w    = tid >> 6;
  const int wq   = w >> 1, wk = w & 1;
  const int l31  = lane & 31, lhi = lane >> 5;

  const float*  qbase  = q  + (size_t)bh * SD;
  const float*  kbase  = k  + (size_t)bh * SD;
  const ushort* kbbase = kb + (size_t)bh * SD;
  const float*  vbase  = v  + (size_t)bh * SD;

  short8 qf[8];
  {
    const float* qrow = qbase + (size_t)(qb * 64 + wq * 32 + l31) * D_DIM;
    #pragma unroll
    for (int s = 0; s < 8; ++s) {
      int d0 = 16 * s + 8 * lhi;
      float4 a = *(const float4*)(qrow + d0);
      float4 b = *(const float4*)(qrow + d0 + 4);
      qf[s] = pack8(a, b);
    }
  }

  float4 kreg[8], vreg[8];
  short8 kreg16[4];

  auto load_k = [&](int kt) {
    int trow = tid >> 2, tc = tid & 3;
    if constexpr (KB16) {
      const ushort* src = kbbase + (size_t)(kt * BC + trow) * D_DIM;
      #pragma unroll
      for (int i = 0; i < 4; ++i)
        kreg16[i] = *(const short8*)(src + tc * 8 + i * 32);
    } else {
      const float* src = kbase + (size_t)(kt * BC + trow) * D_DIM;
      #pragma unroll
      for (int i = 0; i < 4; ++i) {
        int c0 = tc * 8 + i * 32;
        kreg[2 * i]     = *(const float4*)(src + c0);
        kreg[2 * i + 1] = *(const float4*)(src + c0 + 4);
      }
    }
  };
  auto write_k = [&]() {
    int trow = tid >> 2, tc = tid & 3;
    #pragma unroll
    for (int i = 0; i < 4; ++i) {
      int c0 = tc * 8 + i * 32;
      int off = (trow * 256 + c0 * 2) ^ ((trow & 7) << 4);
      if constexpr (KB16)
        *(short8*)(klds + off) = kreg16[i];
      else
        *(short8*)(klds + off) = pack8(kreg[2 * i], kreg[2 * i + 1]);
    }
  };
  auto load_v = [&](int kt) {
    int kp = tid & 31, dg = tid >> 5;
    const float* r0 = vbase + (size_t)(kt * BC + 2 * kp) * D_DIM + dg * 16;
    #pragma unroll
    for (int i = 0; i < 4; ++i) {
      vreg[i]     = *(const float4*)(r0 + 4 * i);
      vreg[4 + i] = *(const float4*)(r0 + D_DIM + 4 * i);
    }
  };
  auto write_v = [&]() {
    int kp = tid & 31, dg = tid >> 5;
    #pragma unroll
    for (int j = 0; j < 16; ++j) {
      int d = dg * 16 + j;
      float lo = vreg[j >> 2][j & 3];
      float hi = vreg[4 + (j >> 2)][j & 3];
      unsigned u = (unsigned)f2bf(lo) | ((unsigned)f2bf(hi) << 16);
      int off = (d * 128 + kp * 4) ^ ((d & 7) << 4);
      *(unsigned*)(vtlds + off) = u;
    }
  };

  auto compute_s = [&]() -> f32x16 {
    f32x16 acc;
    #pragma unroll
    for (int i = 0; i < 16; ++i) acc[i] = 0.f;
    int krow = wk * 32 + l31;
    int base = krow * 256;
    int swz  = (krow & 7) << 4;
    #pragma unroll
    for (int s = 0; s < 8; ++s) {
      int off = (base + 32 * s + 16 * lhi) ^ swz;
      short8 kf = *(const short8*)(klds + off);
      acc = __builtin_amdgcn_mfma_f32_32x32x16_bf16(qf[s], kf, acc, 0, 0, 0);
    }
    return acc;
  };

  float l_lane[16];
  f32x16 o0, o1;
  #pragma unroll
  for (int i = 0; i < 16; ++i) { l_lane[i] = 0.f; o0[i] = 0.f; o1[i] = 0.f; }

  load_k(0); load_v(0);

  for (int kt = 0; kt <= qb; ++kt) {
    write_k(); write_v();
    if (kt < qb) { load_k(kt + 1); load_v(kt + 1); }
    __syncthreads();

    f32x16 acc = compute_s();
    int kcol_l = wk * 32 + l31;
    int kcol = kt * BC + kcol_l;
    bool diag = (kt == qb);
    #pragma unroll
    for (int r = 0; r < 16; ++r) {
      int rl = wq * 32 + (r & 3) + 8 * (r >> 2) + 4 * lhi;
      int qrow = qb * 64 + rl;
      float e = (diag && kcol > qrow) ? 0.f : __expf(acc[r] * SCALE);
      l_lane[r] += e;
      int poff = (rl * 128 + kcol_l * 2) ^ ((rl & 7) << 4);
      *(ushort*)(plds + poff) = f2bf(e);
    }
    __syncthreads();

    #pragma unroll
    for (int s = 0; s < 4; ++s) {
      int prow = wq * 32 + l31;
      int paoff = (prow * 128 + (16 * s + 8 * lhi) * 2) ^ ((prow & 7) << 4);
      short8 pa = *(const short8*)(plds + paoff);
      int kko = (16 * s + 8 * lhi) * 2;
      int d0 = wk * 64 + l31;
      int d1 = d0 + 32;
      int off0 = (d0 * 128 + kko) ^ ((d0 & 7) << 4);
      int off1 = (d1 * 128 + kko) ^ ((d1 & 7) << 4);
      short8 vb0 = *(const short8*)(vtlds + off0);
      short8 vb1 = *(const short8*)(vtlds + off1);
      o0 = __builtin_amdgcn_mfma_f32_32x32x16_bf16(pa, vb0, o0, 0, 0, 0);
      o1 = __builtin_amdgcn_mfma_f32_32x32x16_bf16(pa, vb1, o1, 0, 0, 0);
    }
    __syncthreads();
  }

  #pragma unroll
  for (int r = 0; r < 16; ++r) {
    float x = l_lane[r];
    x += __shfl_xor(x, 1);  x += __shfl_xor(x, 2);  x += __shfl_xor(x, 4);
    x += __shfl_xor(x, 8);  x += __shfl_xor(x, 16);
    l_lane[r] = x;
  }
  if (l31 == 0) {
    #pragma unroll
    for (int r = 0; r < 16; ++r) {
      int rl = wq * 32 + (r & 3) + 8 * (r >> 2) + 4 * lhi;
      lred[wk][rl] = l_lane[r];
    }
  }
  __syncthreads();

  if constexpr (PUB) {
    if (tid < 64)
      atomicExch(&lsum_out[(size_t)bh * S_LEN + qb * 64 + tid],
                 lred[0][tid] + lred[1][tid]);
    __threadfence();
    __syncthreads();
    if (tid == 0) atomicExch(&flags[bh * 32 + qb], 1u);
  }

  float inv_l[16];
  #pragma unroll
  for (int r = 0; r < 16; ++r) {
    int rl = wq * 32 + (r & 3) + 8 * (r >> 2) + 4 * lhi;
    inv_l[r] = 1.0f / (lred[0][rl] + lred[1][rl]);
  }
  #pragma unroll
  for (int r = 0; r < 16; ++r) {
    int rl = wq * 32 + (r & 3) + 8 * (r >> 2) + 4 * lhi;
    size_t obase = (size_t)(bh * S_LEN + qb * 64 + rl) * D_DIM;
    ctx[obase + wk * 64 + l31]      = o0[r] * inv_l[r];
    ctx[obase + wk * 64 + 32 + l31] = o1[r] * inv_l[r];
  }
}

// ====== B-item: v4 streamer. WAIT: consume published lsum; else pass-1. ======
template <bool KB16, bool WAIT>
__device__ __forceinline__ void do_B(
    int bh, int panel,
    const float* __restrict__ q, const float* __restrict__ k,
    const ushort* __restrict__ kb, float* __restrict__ lsum,
    unsigned* __restrict__ flags, float* __restrict__ wts) {
  const int tid  = threadIdx.x;
  const int lane = tid & 63;
  const int w    = tid >> 6;
  const int l31  = lane & 31, lhi = lane >> 5;

  const int qrow0 = panel * 128 + w * 32;
  float* wbase = wts + ((size_t)bh * S_LEN + qrow0) * S_LEN;

  if constexpr (WAIT) {
    if (tid == 0) {
      while (atomicAdd(&flags[bh * 32 + 2 * panel], 0u) == 0u)
        __builtin_amdgcn_s_sleep(8);
      while (atomicAdd(&flags[bh * 32 + 2 * panel + 1], 0u) == 0u)
        __builtin_amdgcn_s_sleep(8);
    }
    __syncthreads();
  }

  short8 qf[8];
  {
    const float* qrow = q + ((size_t)bh * S_LEN + qrow0 + l31) * D_DIM;
    #pragma unroll
    for (int s = 0; s < 8; ++s) {
      int d0 = 16 * s + 8 * lhi;
      float4 a = *(const float4*)(qrow + d0);
      float4 b = *(const float4*)(qrow + d0 + 4);
      qf[s] = pack8(a, b);
    }
  }

  const int qmax = qrow0 + 31;
  const ushort* kbb = kb + (size_t)bh * SD;
  const float*  kfb = k  + (size_t)bh * SD;

  float invl[16];
  if constexpr (WAIT) {
    #pragma unroll
    for (int r = 0; r < 16; ++r) {
      int rl = (r & 3) + 8 * (r >> 2) + 4 * lhi;
      invl[r] = 1.0f / atomicAdd(&lsum[(size_t)bh * S_LEN + qrow0 + rl], 0.f);
    }
  } else {
    float l_lane[16];
    #pragma unroll
    for (int r = 0; r < 16; ++r) l_lane[r] = 0.f;
    const int nkt = qmax / 64 + 1;
    for (int kt = 0; kt < nkt; ++kt) {
      f32x16 a0, a1;
      #pragma unroll
      for (int i = 0; i < 16; ++i) { a0[i] = 0.f; a1[i] = 0.f; }
      if constexpr (KB16) {
        const ushort* k0 = kbb + (size_t)(kt * 64 + l31) * D_DIM;
        const ushort* k1 = k0 + 32 * D_DIM;
        #pragma unroll
        for (int s8 = 0; s8 < 8; ++s8) {
          int d0 = 16 * s8 + 8 * lhi;
          a0 = __builtin_amdgcn_mfma_f32_32x32x16_bf16(qf[s8], *(const short8*)(k0 + d0), a0, 0, 0, 0);
          a1 = __builtin_amdgcn_mfma_f32_32x32x16_bf16(qf[s8], *(const short8*)(k1 + d0), a1, 0, 0, 0);
        }
      } else {
        const float* k0 = kfb + (size_t)(kt * 64 + l31) * D_DIM;
        const float* k1 = k0 + 32 * D_DIM;
        #pragma unroll
        for (int s8 = 0; s8 < 8; ++s8) {
          int d0 = 16 * s8 + 8 * lhi;
          short8 kf0 = pack8(*(const float4*)(k0 + d0), *(const float4*)(k0 + d0 + 4));
          short8 kf1 = pack8(*(const float4*)(k1 + d0), *(const float4*)(k1 + d0 + 4));
          a0 = __builtin_amdgcn_mfma_f32_32x32x16_bf16(qf[s8], kf0, a0, 0, 0, 0);
          a1 = __builtin_amdgcn_mfma_f32_32x32x16_bf16(qf[s8], kf1, a1, 0, 0, 0);
        }
      }
      const int kc0 = kt * 64 + l31, kc1 = kc0 + 32;
      #pragma unroll
      for (int r = 0; r < 16; ++r) {
        int qr = qrow0 + (r & 3) + 8 * (r >> 2) + 4 * lhi;
        float e0 = (kc0 > qr) ? 0.f : __expf(a0[r] * SCALE);
        float e1 = (kc1 > qr) ? 0.f : __expf(a1[r] * SCALE);
        l_lane[r] += e0 + e1;
      }
    }
    #pragma unroll
    for (int r = 0; r < 16; ++r) {
      float x = l_lane[r];
      x += __shfl_xor(x, 1);  x += __shfl_xor(x, 2);  x += __shfl_xor(x, 4);
      x += __shfl_xor(x, 8);  x += __shfl_xor(x, 16);
      invl[r] = 1.0f / x;
    }
  }

  const int nkg = qmax / 256 + 1;
  for (int kg = 0; kg < nkg; ++kg) {
    f32x16 ac[8];
    #pragma unroll
    for (int t = 0; t < 8; ++t)
      #pragma unroll
      for (int i = 0; i < 16; ++i) ac[t][i] = 0.f;

    #pragma unroll
    for (int t = 0; t < 4; ++t) {
      const int tc0 = kg * 256 + t * 64;
      if (tc0 <= qmax) {
        if constexpr (KB16) {
          const ushort* k0 = kbb + (size_t)(tc0 + l31) * D_DIM;
          const ushort* k1 = k0 + 32 * D_DIM;
          #pragma unroll
          for (int s8 = 0; s8 < 8; ++s8) {
            int d0 = 16 * s8 + 8 * lhi;
            ac[2 * t]     = __builtin_amdgcn_mfma_f32_32x32x16_bf16(qf[s8], *(const short8*)(k0 + d0), ac[2 * t], 0, 0, 0);
            ac[2 * t + 1] = __builtin_amdgcn_mfma_f32_32x32x16_bf16(qf[s8], *(const short8*)(k1 + d0), ac[2 * t + 1], 0, 0, 0);
          }
        } else {
          const float* k0 = kfb + (size_t)(tc0 + l31) * D_DIM;
          const float* k1 = k0 + 32 * D_DIM;
          #pragma unroll
          for (int s8 = 0; s8 < 8; ++s8) {
            int d0 = 16 * s8 + 8 * lhi;
            short8 kf0 = pack8(*(const float4*)(k0 + d0), *(const float4*)(k0 + d0 + 4));
            short8 kf1 = pack8(*(const float4*)(k1 + d0), *(const float4*)(k1 + d0 + 4));
            ac[2 * t]     = __builtin_amdgcn_mfma_f32_32x32x16_bf16(qf[s8], kf0, ac[2 * t], 0, 0, 0);
            ac[2 * t + 1] = __builtin_amdgcn_mfma_f32_32x32x16_bf16(qf[s8], kf1, ac[2 * t + 1], 0, 0, 0);
          }
        }
      }
    }

    #pragma unroll
    for (int t = 0; t < 4; ++t) {
      const int kc0 = kg * 256 + t * 64 + l31;
      const int kc1 = kc0 + 32;
      #pragma unroll
      for (int r = 0; r < 16; ++r) {
        int qr = qrow0 + (r & 3) + 8 * (r >> 2) + 4 * lhi;
        ac[2 * t][r]     = (kc0 > qr) ? 0.f : __expf(ac[2 * t][r] * SCALE) * invl[r];
        ac[2 * t + 1][r] = (kc1 > qr) ? 0.f : __expf(ac[2 * t + 1][r] * SCALE) * invl[r];
      }
    }

    float* gbase = wbase + kg * 256 + lane;
    #pragma unroll
    for (int r = 0; r < 16; ++r) {
      int rA = (r & 3) + 8 * (r >> 2);
      float* rpA = gbase + (size_t)rA * S_LEN;
      float* rpB = gbase + (size_t)(rA + 4) * S_LEN;
      #pragma unroll
      for (int t = 0; t < 4; ++t) {
        float sA = __shfl(ac[2 * t + 1][r], lane ^ 32);
        float vA = lhi ? sA : ac[2 * t][r];
        __builtin_nontemporal_store(vA, rpA + t * 64);
      }
      #pragma unroll
      for (int t = 0; t < 4; ++t) {
        float sB = __shfl(ac[2 * t][r], lane ^ 32);
        float vB = lhi ? ac[2 * t + 1][r] : sB;
        __builtin_nontemporal_store(vB, rpB + t * 64);
      }
    }
  }

  fv4 z = (fv4)0.f;
  const int c0 = nkg * 256;
  for (int rr = 0; rr < 32; ++rr) {
    float* rowp = wbase + (size_t)rr * S_LEN;
    for (int c = c0 + lane * 4; c < S_LEN; c += 256)
      __builtin_nontemporal_store(z, (fv4*)(rowp + c));
  }
}

// ========== mega2: per-XCD ticket queue, A-then-B per panel group ============
// Per XCD: 16 groups j (panel p=15-j): tickets j*24+{0..15}=A (8 heads x
// qb=2p+1 then 2p), j*24+{16..23}=B (8 heads, panel p). B's deps are EARLIER
// tickets on the SAME counter: claimed => running => will finish. Deadlock-
// free with no dispatch-order assumption. Counter choice bid&7 keeps claims
// per counter exact; physical XCD locality follows HW round-robin heuristic.
template <bool KB16>
__global__ __launch_bounds__(256, 3) void attn_mega2_kernel(
    const float* __restrict__ q, const float* __restrict__ k,
    const ushort* __restrict__ kb, const float* __restrict__ v,
    float* __restrict__ ctx, float* __restrict__ wts,
    unsigned* __restrict__ cnt, unsigned* __restrict__ flags,
    float* __restrict__ lsum) {
  __shared__ __align__(16) char klds[BC * 256];
  __shared__ __align__(16) char vtlds[D_DIM * 128];
  __shared__ __align__(16) char plds[64 * 128];
  __shared__ float lred[2][64];
  __shared__ int sh_s;

  const int xcd = blockIdx.x & 7;
  if (threadIdx.x == 0) sh_s = (int)atomicAdd(&cnt[xcd * 16], 1u);
  __syncthreads();
  const int s = sh_s;

  const int j = s / 24;
  const int r = s - j * 24;
  const int p = 15 - j;

  if (r < 16) {
    int bh = xcd + 8 * (r & 7);
    int qb = 2 * p + (r < 8 ? 1 : 0);
    do_A<KB16, true>(bh, qb, q, k, kb, v, ctx, lsum, flags,
                     klds, vtlds, plds, lred);
  } else {
    int bh = xcd + 8 * (r - 16);
    do_B<KB16, true>(bh, p, q, k, kb, lsum, flags, wts);
  }
}

// ================== fallback: R12-style static combo (tiny ws) ===============
__global__ __launch_bounds__(256, 3) void attn_combo_kernel(
    const float* __restrict__ q, const float* __restrict__ k,
    const float* __restrict__ v, float* __restrict__ ctx,
    float* __restrict__ wts) {
  __shared__ __align__(16) char klds[BC * 256];
  __shared__ __align__(16) char vtlds[D_DIM * 128];
  __shared__ __align__(16) char plds[64 * 128];
  __shared__ float lred[2][64];

  const int bid = blockIdx.x;
  const int xcd = bid & 7;
  const int seq = bid >> 3;
  const int m   = seq % 3;

  if (m < 2) {
    int a_idx = (seq / 3) * 2 + m;
    int bh    = xcd + 8 * (a_idx & 7);
    int qb    = 31 - (a_idx >> 3);
    do_A<false, false>(bh, qb, q, k, nullptr, v, ctx, nullptr, nullptr,
                       klds, vtlds, plds, lred);
  } else {
    int b_idx = seq / 3;
    int bh    = xcd + 8 * (b_idx & 7);
    int panel = 15 - (b_idx >> 3);
    do_B<false, false>(bh, panel, q, k, nullptr, nullptr, nullptr, wts);
  }
}

extern "C" void kernel_launch(void* const* d_in, const int* in_sizes, int n_in,
                              void* d_out, int out_size, void* d_ws, size_t ws_size,
                              hipStream_t stream) {
  const float* q = (const float*)d_in[0];
  const float* k = (const float*)d_in[1];
  const float* v = (const float*)d_in[2];
  float* ctx = (float*)d_out;
  float* wts = ctx + (size_t)BH_N * SD;

  unsigned* cnt   = (unsigned*)d_ws;
  unsigned* flags = (unsigned*)((char*)d_ws + FLAGS_OFF);
  float*    lsum  = (float*)((char*)d_ws + LSUM_OFF);
  ushort*   kb16  = (ushort*)((char*)d_ws + KB16_OFF);

  if (ws_size >= WS_SYNC16) {
    init_kernel<<<dim3(1), dim3(256), 0, stream>>>(cnt);
    cvt_k_kernel<<<dim3(2048), dim3(256), 0, stream>>>(k, kb16);
    attn_mega2_kernel<true><<<dim3(3072), dim3(256), 0, stream>>>(
        q, k, kb16, v, ctx, wts, cnt, flags, lsum);
  } else if (ws_size >= WS_SYNC) {
    init_kernel<<<dim3(1), dim3(256), 0, stream>>>(cnt);
    attn_mega2_kernel<false><<<dim3(3072), dim3(256), 0, stream>>>(
        q, k, kb16, v, ctx, wts, cnt, flags, lsum);
  } else {
    attn_combo_kernel<<<dim3(3072), dim3(256), 0, stream>>>(
        q, k, v, ctx, wts);
  }
}

// Round 15
// 539.406 us; speedup vs baseline: 5.1902x; 5.1902x over previous
//
#include <hip/hip_runtime.h>
#include <hip/hip_bf16.h>

#define S_LEN 2048
#define D_DIM 128
#define BH_N  64
#define BC    64
#define NTILE (S_LEN / BC)
#define SCALE 0.08838834764831845f
#define SD    (S_LEN * D_DIM)
#define LSUM_BYTES (BH_N * S_LEN * 4)
#define WS_NEED (LSUM_BYTES + (size_t)BH_N * SD * 2)

typedef __attribute__((ext_vector_type(8)))  short short8;
typedef __attribute__((ext_vector_type(16))) float f32x16;
typedef __attribute__((ext_vector_type(4)))  float fv4;

__device__ __forceinline__ ushort f2bf(float f) {
  union { float f; unsigned u; } x; x.f = f;
  unsigned r = x.u + 0x7FFFu + ((x.u >> 16) & 1u);
  return (ushort)(r >> 16);
}

__device__ __forceinline__ short8 pack8(float4 a, float4 b) {
  short8 p;
  p[0] = (short)f2bf(a.x); p[1] = (short)f2bf(a.y);
  p[2] = (short)f2bf(a.z); p[3] = (short)f2bf(a.w);
  p[4] = (short)f2bf(b.x); p[5] = (short)f2bf(b.y);
  p[6] = (short)f2bf(b.z); p[7] = (short)f2bf(b.w);
  return p;
}

// ===================== Kernel 0: K fp32 -> bf16 (RNE, = f2bf) ================
__global__ __launch_bounds__(256) void cvt_k_kernel(
    const float* __restrict__ k, ushort* __restrict__ kb) {
  size_t total = (size_t)BH_N * SD / 8;
  for (size_t i = (size_t)blockIdx.x * 256 + threadIdx.x; i < total;
       i += (size_t)gridDim.x * 256) {
    float4 a = *(const float4*)(k + i * 8);
    float4 b = *(const float4*)(k + i * 8 + 4);
    *(short8*)(kb + i * 8) = pack8(a, b);
  }
}

// ============================ Kernel A: flash ctx + l ========================
__device__ __forceinline__ void map_block_a(int bid, int& bh, int& qb) {
  int xcd  = bid & 7;
  int rest = bid >> 3;
  bh = (rest >> 5) * 8 + xcd;
  qb = (NTILE - 1) - (rest & 31);
}

template <bool KB16>
__global__ __launch_bounds__(256, 2) void attn_flash_kernel(
    const float* __restrict__ q, const float* __restrict__ k,
    const ushort* __restrict__ kb, const float* __restrict__ v,
    float* __restrict__ ctx, float* __restrict__ lsum_out) {
  __shared__ __align__(16) char klds[BC * 256];
  __shared__ __align__(16) char vtlds[D_DIM * 128];
  __shared__ __align__(16) char plds[64 * 128];
  __shared__ float lred[2][64];

  const int tid  = threadIdx.x;
  const int lane = tid & 63;
  const int w    = tid >> 6;
  const int wq   = w >> 1, wk = w & 1;
  const int l31  = lane & 31, lhi = lane >> 5;

  int bh, qb;
  map_block_a(blockIdx.x, bh, qb);

  const float*  qbase  = q  + (size_t)bh * SD;
  const float*  kbase  = k  + (size_t)bh * SD;
  const ushort* kbbase = kb + (size_t)bh * SD;
  const float*  vbase  = v  + (size_t)bh * SD;

  short8 qf[8];
  {
    const float* qrow = qbase + (size_t)(qb * 64 + wq * 32 + l31) * D_DIM;
    #pragma unroll
    for (int s = 0; s < 8; ++s) {
      int d0 = 16 * s + 8 * lhi;
      float4 a = *(const float4*)(qrow + d0);
      float4 b = *(const float4*)(qrow + d0 + 4);
      qf[s] = pack8(a, b);
    }
  }

  float4 kreg[8], vreg[8];
  short8 kreg16[4];

  auto load_k = [&](int kt) {
    int trow = tid >> 2, tc = tid & 3;
    if constexpr (KB16) {
      const ushort* src = kbbase + (size_t)(kt * BC + trow) * D_DIM;
      #pragma unroll
      for (int i = 0; i < 4; ++i)
        kreg16[i] = *(const short8*)(src + tc * 8 + i * 32);
    } else {
      const float* src = kbase + (size_t)(kt * BC + trow) * D_DIM;
      #pragma unroll
      for (int i = 0; i < 4; ++i) {
        int c0 = tc * 8 + i * 32;
        kreg[2 * i]     = *(const float4*)(src + c0);
        kreg[2 * i + 1] = *(const float4*)(src + c0 + 4);
      }
    }
  };
  auto write_k = [&]() {
    int trow = tid >> 2, tc = tid & 3;
    #pragma unroll
    for (int i = 0; i < 4; ++i) {
      int c0 = tc * 8 + i * 32;
      int off = (trow * 256 + c0 * 2) ^ ((trow & 7) << 4);
      if constexpr (KB16)
        *(short8*)(klds + off) = kreg16[i];
      else
        *(short8*)(klds + off) = pack8(kreg[2 * i], kreg[2 * i + 1]);
    }
  };
  auto load_v = [&](int kt) {
    int kp = tid & 31, dg = tid >> 5;
    const float* r0 = vbase + (size_t)(kt * BC + 2 * kp) * D_DIM + dg * 16;
    #pragma unroll
    for (int i = 0; i < 4; ++i) {
      vreg[i]     = *(const float4*)(r0 + 4 * i);
      vreg[4 + i] = *(const float4*)(r0 + D_DIM + 4 * i);
    }
  };
  auto write_v = [&]() {
    int kp = tid & 31, dg = tid >> 5;
    #pragma unroll
    for (int j = 0; j < 16; ++j) {
      int d = dg * 16 + j;
      float lo = vreg[j >> 2][j & 3];
      float hi = vreg[4 + (j >> 2)][j & 3];
      unsigned u = (unsigned)f2bf(lo) | ((unsigned)f2bf(hi) << 16);
      int off = (d * 128 + kp * 4) ^ ((d & 7) << 4);
      *(unsigned*)(vtlds + off) = u;
    }
  };

  auto compute_s = [&]() -> f32x16 {
    f32x16 acc;
    #pragma unroll
    for (int i = 0; i < 16; ++i) acc[i] = 0.f;
    int krow = wk * 32 + l31;
    int base = krow * 256;
    int swz  = (krow & 7) << 4;
    #pragma unroll
    for (int s = 0; s < 8; ++s) {
      int off = (base + 32 * s + 16 * lhi) ^ swz;
      short8 kf = *(const short8*)(klds + off);
      acc = __builtin_amdgcn_mfma_f32_32x32x16_bf16(qf[s], kf, acc, 0, 0, 0);
    }
    return acc;
  };

  float l_lane[16];
  f32x16 o0, o1;
  #pragma unroll
  for (int i = 0; i < 16; ++i) { l_lane[i] = 0.f; o0[i] = 0.f; o1[i] = 0.f; }

  load_k(0); load_v(0);

  for (int kt = 0; kt <= qb; ++kt) {
    write_k(); write_v();
    if (kt < qb) { load_k(kt + 1); load_v(kt + 1); }
    __syncthreads();

    f32x16 acc = compute_s();
    int kcol_l = wk * 32 + l31;
    int kcol = kt * BC + kcol_l;
    bool diag = (kt == qb);
    #pragma unroll
    for (int r = 0; r < 16; ++r) {
      int rl = wq * 32 + (r & 3) + 8 * (r >> 2) + 4 * lhi;
      int qrow = qb * 64 + rl;
      float e = (diag && kcol > qrow) ? 0.f : __expf(acc[r] * SCALE);
      l_lane[r] += e;
      int poff = (rl * 128 + kcol_l * 2) ^ ((rl & 7) << 4);
      *(ushort*)(plds + poff) = f2bf(e);
    }
    __syncthreads();

    #pragma unroll
    for (int s = 0; s < 4; ++s) {
      int prow = wq * 32 + l31;
      int paoff = (prow * 128 + (16 * s + 8 * lhi) * 2) ^ ((prow & 7) << 4);
      short8 pa = *(const short8*)(plds + paoff);
      int kko = (16 * s + 8 * lhi) * 2;
      int d0 = wk * 64 + l31;
      int d1 = d0 + 32;
      int off0 = (d0 * 128 + kko) ^ ((d0 & 7) << 4);
      int off1 = (d1 * 128 + kko) ^ ((d1 & 7) << 4);
      short8 vb0 = *(const short8*)(vtlds + off0);
      short8 vb1 = *(const short8*)(vtlds + off1);
      o0 = __builtin_amdgcn_mfma_f32_32x32x16_bf16(pa, vb0, o0, 0, 0, 0);
      o1 = __builtin_amdgcn_mfma_f32_32x32x16_bf16(pa, vb1, o1, 0, 0, 0);
    }
    __syncthreads();
  }

  #pragma unroll
  for (int r = 0; r < 16; ++r) {
    float x = l_lane[r];
    x += __shfl_xor(x, 1);  x += __shfl_xor(x, 2);  x += __shfl_xor(x, 4);
    x += __shfl_xor(x, 8);  x += __shfl_xor(x, 16);
    l_lane[r] = x;
  }
  if (l31 == 0) {
    #pragma unroll
    for (int r = 0; r < 16; ++r) {
      int rl = wq * 32 + (r & 3) + 8 * (r >> 2) + 4 * lhi;
      lred[wk][rl] = l_lane[r];
    }
  }
  __syncthreads();

  if (tid < 64)
    lsum_out[(size_t)bh * S_LEN + qb * 64 + tid] = lred[0][tid] + lred[1][tid];

  float inv_l[16];
  #pragma unroll
  for (int r = 0; r < 16; ++r) {
    int rl = wq * 32 + (r & 3) + 8 * (r >> 2) + 4 * lhi;
    inv_l[r] = 1.0f / (lred[0][rl] + lred[1][rl]);
  }
  #pragma unroll
  for (int r = 0; r < 16; ++r) {
    int rl = wq * 32 + (r & 3) + 8 * (r >> 2) + 4 * lhi;
    size_t obase = (size_t)(bh * S_LEN + qb * 64 + rl) * D_DIM;
    ctx[obase + wk * 64 + l31]      = o0[r] * inv_l[r];
    ctx[obase + wk * 64 + 32 + l31] = o1[r] * inv_l[r];
  }
}

// ============ Kernel B v4: barrier-free weights, 1KB row-runs ================
template <bool KB16>
__global__ __launch_bounds__(256) void attn_wts_stream_kernel(
    const float* __restrict__ q, const float* __restrict__ k,
    const ushort* __restrict__ kb, const float* __restrict__ lsum,
    float* __restrict__ wts) {
  const int tid  = threadIdx.x;
  const int lane = tid & 63;
  const int w    = tid >> 6;
  const int l31  = lane & 31, lhi = lane >> 5;

  int bh, panel;
  {
    int bid = blockIdx.x;           // 64 bh x 16 panels of 128 rows
    int xcd = bid & 7, rest = bid >> 3;
    bh    = (rest >> 4) * 8 + xcd;  // all 16 panels of a head on one XCD
    panel = 15 - (rest & 15);       // big panels first
  }

  const int qrow0 = panel * 128 + w * 32;
  float* wbase = wts + ((size_t)bh * S_LEN + qrow0) * S_LEN;

  short8 qf[8];
  {
    const float* qrow = q + ((size_t)bh * S_LEN + qrow0 + l31) * D_DIM;
    #pragma unroll
    for (int s = 0; s < 8; ++s) {
      int d0 = 16 * s + 8 * lhi;
      float4 a = *(const float4*)(qrow + d0);
      float4 b = *(const float4*)(qrow + d0 + 4);
      qf[s] = pack8(a, b);
    }
  }

  float invl[16];
  #pragma unroll
  for (int r = 0; r < 16; ++r) {
    int rl = (r & 3) + 8 * (r >> 2) + 4 * lhi;
    invl[r] = 1.0f / lsum[(size_t)bh * S_LEN + qrow0 + rl];
  }

  const int qmax = qrow0 + 31;
  const int nkg  = qmax / 256 + 1;               // 256-col groups w/ unmasked

  const ushort* kbb = kb + (size_t)bh * SD;
  const float*  kfb = k  + (size_t)bh * SD;

  for (int kg = 0; kg < nkg; ++kg) {
    f32x16 ac[8];
    #pragma unroll
    for (int t = 0; t < 8; ++t)
      #pragma unroll
      for (int i = 0; i < 16; ++i) ac[t][i] = 0.f;

    #pragma unroll
    for (int t = 0; t < 4; ++t) {
      const int tc0 = kg * 256 + t * 64;
      if (tc0 <= qmax) {
        if constexpr (KB16) {
          const ushort* k0 = kbb + (size_t)(tc0 + l31) * D_DIM;
          const ushort* k1 = k0 + 32 * D_DIM;
          #pragma unroll
          for (int s8 = 0; s8 < 8; ++s8) {
            int d0 = 16 * s8 + 8 * lhi;
            short8 kf0 = *(const short8*)(k0 + d0);
            short8 kf1 = *(const short8*)(k1 + d0);
            ac[2 * t]     = __builtin_amdgcn_mfma_f32_32x32x16_bf16(qf[s8], kf0, ac[2 * t], 0, 0, 0);
            ac[2 * t + 1] = __builtin_amdgcn_mfma_f32_32x32x16_bf16(qf[s8], kf1, ac[2 * t + 1], 0, 0, 0);
          }
        } else {
          const float* k0 = kfb + (size_t)(tc0 + l31) * D_DIM;
          const float* k1 = k0 + 32 * D_DIM;
          #pragma unroll
          for (int s8 = 0; s8 < 8; ++s8) {
            int d0 = 16 * s8 + 8 * lhi;
            short8 kf0 = pack8(*(const float4*)(k0 + d0), *(const float4*)(k0 + d0 + 4));
            short8 kf1 = pack8(*(const float4*)(k1 + d0), *(const float4*)(k1 + d0 + 4));
            ac[2 * t]     = __builtin_amdgcn_mfma_f32_32x32x16_bf16(qf[s8], kf0, ac[2 * t], 0, 0, 0);
            ac[2 * t + 1] = __builtin_amdgcn_mfma_f32_32x32x16_bf16(qf[s8], kf1, ac[2 * t + 1], 0, 0, 0);
          }
        }
      }
    }

    #pragma unroll
    for (int t = 0; t < 4; ++t) {
      const int kc0 = kg * 256 + t * 64 + l31;
      const int kc1 = kc0 + 32;
      #pragma unroll
      for (int r = 0; r < 16; ++r) {
        int qr = qrow0 + (r & 3) + 8 * (r >> 2) + 4 * lhi;
        ac[2 * t][r]     = (kc0 > qr) ? 0.f : __expf(ac[2 * t][r] * SCALE) * invl[r];
        ac[2 * t + 1][r] = (kc1 > qr) ? 0.f : __expf(ac[2 * t + 1][r] * SCALE) * invl[r];
      }
    }

    // row-major drain: per row, 4 consecutive 256B chunks (1KB run)
    float* gbase = wbase + kg * 256 + lane;
    #pragma unroll
    for (int r = 0; r < 16; ++r) {
      int rA = (r & 3) + 8 * (r >> 2);
      float* rpA = gbase + (size_t)rA * S_LEN;
      float* rpB = gbase + (size_t)(rA + 4) * S_LEN;
      #pragma unroll
      for (int t = 0; t < 4; ++t) {
        float sA = __shfl(ac[2 * t + 1][r], lane ^ 32);
        float vA = lhi ? sA : ac[2 * t][r];
        __builtin_nontemporal_store(vA, rpA + t * 64);
      }
      #pragma unroll
      for (int t = 0; t < 4; ++t) {
        float sB = __shfl(ac[2 * t][r], lane ^ 32);
        float vB = lhi ? ac[2 * t + 1][r] : sB;
        __builtin_nontemporal_store(vB, rpB + t * 64);
      }
    }
  }

  // zero-fill the fully-masked tail of the wave's 32 rows (1KB per instr)
  fv4 z = (fv4)0.f;
  const int c0 = nkg * 256;
  for (int rr = 0; rr < 32; ++rr) {
    float* rowp = wbase + (size_t)rr * S_LEN;
    for (int c = c0 + lane * 4; c < S_LEN; c += 256)
      __builtin_nontemporal_store(z, (fv4*)(rowp + c));
  }
}

extern "C" void kernel_launch(void* const* d_in, const int* in_sizes, int n_in,
                              void* d_out, int out_size, void* d_ws, size_t ws_size,
                              hipStream_t stream) {
  const float* q = (const float*)d_in[0];
  const float* k = (const float*)d_in[1];
  const float* v = (const float*)d_in[2];
  float* ctx = (float*)d_out;
  float* wts = ctx + (size_t)BH_N * SD;
  float*  lsum = (float*)d_ws;
  ushort* kb16 = (ushort*)((char*)d_ws + LSUM_BYTES);

  const bool fast = ws_size >= WS_NEED;

  if (fast) {
    cvt_k_kernel<<<dim3(2048), dim3(256), 0, stream>>>(k, kb16);
    attn_flash_kernel<true><<<dim3(BH_N * NTILE), dim3(256), 0, stream>>>(
        q, k, kb16, v, ctx, lsum);
    attn_wts_stream_kernel<true><<<dim3(BH_N * 16), dim3(256), 0, stream>>>(
        q, k, kb16, lsum, wts);
  } else {
    attn_flash_kernel<false><<<dim3(BH_N * NTILE), dim3(256), 0, stream>>>(
        q, k, kb16, v, ctx, lsum);
    attn_wts_stream_kernel<false><<<dim3(BH_N * 16), dim3(256), 0, stream>>>(
        q, k, kb16, lsum, wts);
  }
}